// Round 1
// baseline (3245.712 us; speedup 1.0000x reference)
//
#include <hip/hip_runtime.h>

#define HD    256
#define HD2   128
#define SDIM  512
#define GNUM  64
#define NN    100000
#define NE    200000
#define NENT  20000
#define NREL  500
#define BNUM  32
#define SEQL  10

// ---------------- small per-relation kernels ----------------

__global__ void k_rel_feat(const float* __restrict__ rel_emb, const float* __restrict__ rel_mem,
                           const float* __restrict__ W, const float* __restrict__ b,
                           float* __restrict__ rel_feat) {
    __shared__ float s[768];
    int r = blockIdx.x, j = threadIdx.x;
    for (int k = j; k < 768; k += 256)
        s[k] = (k < 512) ? rel_emb[r * 512 + k] : rel_mem[r * 256 + (k - 512)];
    __syncthreads();
    float acc = b[j];
    for (int k = 0; k < 768; ++k) acc += s[k] * W[k * 256 + j];
    rel_feat[r * 256 + j] = acc;
}

// ea1 = rel_feat @ Wn1 ; er1 = relu(rel_feat @ Wr1)
__global__ void k_rel_l1(const float* __restrict__ rel_feat, const float* __restrict__ Wn1,
                         const float* __restrict__ Wr1, float* __restrict__ ea1,
                         float* __restrict__ er1) {
    __shared__ float s[256];
    int r = blockIdx.x, j = threadIdx.x;
    s[j] = rel_feat[r * 256 + j];
    __syncthreads();
    if (j < 128) {
        float acc = 0.f;
        for (int k = 0; k < 256; ++k) acc += s[k] * Wn1[k * 128 + j];
        ea1[r * 128 + j] = acc;
    } else {
        int jj = j - 128;
        float acc = 0.f;
        for (int k = 0; k < 256; ++k) acc += s[k] * Wr1[k * 128 + jj];
        er1[r * 128 + jj] = fmaxf(acc, 0.f);
    }
}

// er2 = relu(er1 @ Wr2) ; eb2 = er1 @ Wn2
__global__ void k_rel_l2(const float* __restrict__ er1, const float* __restrict__ Wr2,
                         const float* __restrict__ Wn2, float* __restrict__ er2,
                         float* __restrict__ eb2) {
    __shared__ float s[128];
    int r = blockIdx.x, j = threadIdx.x;
    if (j < 128) s[j] = er1[r * 128 + j];
    __syncthreads();
    float a = 0.f, c = 0.f;
    for (int k = 0; k < 128; ++k) {
        float v = s[k];
        a += v * Wr2[k * 256 + j];
        c += v * Wn2[k * 256 + j];
    }
    er2[r * 256 + j] = fmaxf(a, 0.f);
    eb2[r * 256 + j] = c;
}

// ---------------- per-entity kernels (16 rows per block) ----------------

__global__ void __launch_bounds__(256) k_ent_feat(const float* __restrict__ ee,
                                                  const float* __restrict__ em,
                                                  const float* __restrict__ W,
                                                  const float* __restrict__ b,
                                                  float* __restrict__ out) {
    __shared__ float s[16 * 768];
    int r0 = blockIdx.x * 16, tid = threadIdx.x;
    for (int idx = tid; idx < 16 * 768; idx += 256) {
        int r = idx / 768, k = idx - r * 768;
        int ent = r0 + r;
        s[idx] = (k < 512) ? ee[ent * 512 + k] : em[ent * 256 + (k - 512)];
    }
    __syncthreads();
    float acc[16];
#pragma unroll
    for (int r = 0; r < 16; ++r) acc[r] = 0.f;
    int j = tid;
    for (int k = 0; k < 768; ++k) {
        float w = W[k * 256 + j];
#pragma unroll
        for (int r = 0; r < 16; ++r) acc[r] += s[r * 768 + k] * w;
    }
    float bb = b[j];
    for (int r = 0; r < 16; ++r) out[(r0 + r) * 256 + j] = acc[r] + bb;
}

// ha1 = ent_feat @ Wn1 ; hb1 = ent_feat @ Wl1
__global__ void __launch_bounds__(256) k_ent_l1(const float* __restrict__ ent_feat,
                                                const float* __restrict__ Wn1,
                                                const float* __restrict__ Wl1,
                                                float* __restrict__ ha1,
                                                float* __restrict__ hb1) {
    __shared__ float s[16 * 256];
    int r0 = blockIdx.x * 16, tid = threadIdx.x;
    for (int idx = tid; idx < 16 * 256; idx += 256) s[idx] = ent_feat[r0 * 256 + idx];
    __syncthreads();
    float acc[16];
#pragma unroll
    for (int r = 0; r < 16; ++r) acc[r] = 0.f;
    const float* Wc;
    int jj;
    if (tid < 128) { Wc = Wn1; jj = tid; } else { Wc = Wl1; jj = tid - 128; }
    for (int k = 0; k < 256; ++k) {
        float w = Wc[k * 128 + jj];
#pragma unroll
        for (int r = 0; r < 16; ++r) acc[r] += s[r * 256 + k] * w;
    }
    float* out = (tid < 128) ? ha1 : hb1;
    for (int r = 0; r < 16; ++r) out[(r0 + r) * 128 + jj] = acc[r];
}

// ---------------- the big fused edge kernel ----------------
// For 16 edges: t1 = text@Wt1, t2 = text@Wt2 (single pass over text),
// scatter msg1 = t1 + ha1[nid[src]] - ea1[et] into agg1,
// scatter (t2 - eb2[et]) into agg2, count deg.
__global__ void __launch_bounds__(384) k_edge(const float* __restrict__ text,
                                              const int* __restrict__ esrc,
                                              const int* __restrict__ edst,
                                              const int* __restrict__ etype,
                                              const int* __restrict__ node_ids,
                                              const float* __restrict__ Wt1,
                                              const float* __restrict__ Wt2,
                                              const float* __restrict__ ha1,
                                              const float* __restrict__ ea1,
                                              const float* __restrict__ eb2,
                                              float* __restrict__ agg1,
                                              float* __restrict__ agg2,
                                              float* __restrict__ deg) {
    __shared__ float s[16 * 512];
    __shared__ int s_src[16], s_dst[16], s_et[16];
    int e0 = blockIdx.x * 16, tid = threadIdx.x;
    for (int idx = tid; idx < 16 * 512; idx += 384) s[idx] = text[(size_t)e0 * 512 + idx];
    if (tid < 16) s_src[tid] = esrc[e0 + tid];
    else if (tid < 32) s_dst[tid - 16] = edst[e0 + tid - 16];
    else if (tid < 48) s_et[tid - 32] = etype[e0 + tid - 32];
    __syncthreads();
    float acc[16];
#pragma unroll
    for (int r = 0; r < 16; ++r) acc[r] = 0.f;
    const float* Wc;
    int jj, ldw;
    if (tid < 128) { Wc = Wt1; jj = tid; ldw = 128; }
    else           { Wc = Wt2; jj = tid - 128; ldw = 256; }
    for (int k = 0; k < 512; ++k) {
        float w = Wc[k * ldw + jj];
#pragma unroll
        for (int r = 0; r < 16; ++r) acc[r] += s[r * 512 + k] * w;
    }
    if (tid < 128) {
        for (int r = 0; r < 16; ++r) {
            int src = s_src[r], dst = s_dst[r], et = s_et[r];
            int nid = node_ids[src];
            float v = acc[r] + ha1[nid * 128 + jj] - ea1[et * 128 + jj];
            atomicAdd(&agg1[(size_t)dst * 128 + jj], v);
        }
    } else {
        for (int r = 0; r < 16; ++r) {
            int dst = s_dst[r], et = s_et[r];
            float v = acc[r] - eb2[et * 256 + jj];
            atomicAdd(&agg2[(size_t)dst * 256 + jj], v);
        }
    }
    if (tid == 0)
        for (int r = 0; r < 16; ++r) atomicAdd(&deg[s_dst[r]], 1.0f);
}

// h1 = relu(agg1/deg + hb1[nid] + b1)   (in place over agg1)
__global__ void k_h1(float* __restrict__ agg1, const float* __restrict__ deg,
                     const float* __restrict__ hb1, const float* __restrict__ b1,
                     const int* __restrict__ node_ids) {
    int idx = blockIdx.x * 256 + threadIdx.x;
    int n = idx >> 7, j = idx & 127;
    float d = fmaxf(deg[n], 1.f);
    int nid = node_ids[n];
    float v = agg1[idx] / d + hb1[nid * 128 + j] + b1[j];
    agg1[idx] = fmaxf(v, 0.f);
}

// s1[dst] += h1[src]
__global__ void k_s1(const float* __restrict__ h1, const int* __restrict__ esrc,
                     const int* __restrict__ edst, float* __restrict__ s1) {
    int e = blockIdx.x * 2 + (threadIdx.x >> 7);
    int j = threadIdx.x & 127;
    int src = esrc[e], dst = edst[e];
    atomicAdd(&s1[(size_t)dst * 128 + j], h1[(size_t)src * 128 + j]);
}

// h2 = relu((agg2 + s1@Wn2)/deg + h1@Wl2 + b2)   (in place over agg2)
__global__ void __launch_bounds__(256) k_h2(float* __restrict__ agg2,
                                            const float* __restrict__ s1,
                                            const float* __restrict__ h1,
                                            const float* __restrict__ deg,
                                            const float* __restrict__ Wn2,
                                            const float* __restrict__ Wl2,
                                            const float* __restrict__ b2) {
    __shared__ float ss[16 * 128], sh[16 * 128];
    int n0 = blockIdx.x * 16, tid = threadIdx.x;
    for (int idx = tid; idx < 16 * 128; idx += 256) {
        ss[idx] = s1[(size_t)n0 * 128 + idx];
        sh[idx] = h1[(size_t)n0 * 128 + idx];
    }
    __syncthreads();
    float aa[16], ab[16];
#pragma unroll
    for (int r = 0; r < 16; ++r) { aa[r] = 0.f; ab[r] = 0.f; }
    for (int k = 0; k < 128; ++k) {
        float w1 = Wn2[k * 256 + tid];
        float w2 = Wl2[k * 256 + tid];
#pragma unroll
        for (int r = 0; r < 16; ++r) {
            aa[r] += ss[r * 128 + k] * w1;
            ab[r] += sh[r * 128 + k] * w2;
        }
    }
    float bb = b2[tid];
    for (int r = 0; r < 16; ++r) {
        int n = n0 + r;
        float d = fmaxf(deg[n], 1.f);
        float v = (agg2[(size_t)n * 256 + tid] + aa[r]) / d + ab[r] + bb;
        agg2[(size_t)n * 256 + tid] = fmaxf(v, 0.f);
    }
}

__device__ __forceinline__ int lower_bound_i(const int* __restrict__ a, int n, int v) {
    int lo = 0, hi = n;
    while (lo < hi) {
        int m = (lo + hi) >> 1;
        if (a[m] < v) lo = m + 1; else hi = m;
    }
    return lo;
}

// per-graph max over node features (h2 >= 0, so int atomicMax on float bits is valid; init 0)
__global__ void k_gmax_nodes(const float* __restrict__ h2, const int* __restrict__ n2g,
                             float* __restrict__ gn) {
    int g = blockIdx.x, q = blockIdx.y, j = threadIdx.x;
    int lo = lower_bound_i(n2g, NN, g);
    int hi = lower_bound_i(n2g, NN, g + 1);
    float mx = 0.f;
    for (int n = lo + q; n < hi; n += 4) mx = fmaxf(mx, h2[(size_t)n * 256 + j]);
    atomicMax((int*)&gn[g * 256 + j], __float_as_int(mx));
}

// per-graph max over edge features: e2[e] = er2[etype[e]]
__global__ void k_gmax_edges(const float* __restrict__ er2, const int* __restrict__ e2g,
                             const int* __restrict__ etype, float* __restrict__ ge) {
    int g = blockIdx.x, q = blockIdx.y, j = threadIdx.x;
    int lo = lower_bound_i(e2g, NE, g);
    int hi = lower_bound_i(e2g, NE, g + 1);
    float mx = 0.f;
    for (int e = lo + q; e < hi; e += 4) {
        int et = etype[e];
        mx = fmaxf(mx, er2[et * 256 + j]);
    }
    atomicMax((int*)&ge[g * 256 + j], __float_as_int(mx));
}

__global__ void k_out(const float* __restrict__ gn, const float* __restrict__ ge,
                      const int* __restrict__ time_idx, const int* __restrict__ lens,
                      float* __restrict__ out) {
    int idx = blockIdx.x * 256 + threadIdx.x;
    const int NOUT = BNUM * SEQL * 512;
    if (idx < NOUT) {
        int j = idx & 511;
        int bt = idx >> 9;
        int b = bt / SEQL, t = bt - b * SEQL;
        float v = 0.f;
        if (t < lens[b]) {
            int g = time_idx[bt];
            v = (j < 256) ? gn[g * 256 + j] : ge[g * 256 + (j - 256)];
        }
        out[idx] = v;
    } else if (idx < NOUT + BNUM) {
        int b = idx - NOUT;
        out[idx] = (float)lens[b];  // tuple output 1 read back as float32 values
    }
}

// ---------------- launch ----------------

extern "C" void kernel_launch(void* const* d_in, const int* in_sizes, int n_in,
                              void* d_out, int out_size, void* d_ws, size_t ws_size,
                              hipStream_t stream) {
    const int*   node_ids  = (const int*)d_in[0];
    const int*   edge_src  = (const int*)d_in[1];
    const int*   edge_dst  = (const int*)d_in[2];
    const int*   edge_type = (const int*)d_in[3];
    const int*   node2g    = (const int*)d_in[4];
    const int*   edge2g    = (const int*)d_in[5];
    const float* text_emb  = (const float*)d_in[6];
    const int*   time_idx  = (const int*)d_in[7];
    const int*   lens      = (const int*)d_in[8];
    const float* ent_emb   = (const float*)d_in[9];
    const float* ent_mem   = (const float*)d_in[10];
    const float* rel_emb   = (const float*)d_in[11];
    const float* rel_mem   = (const float*)d_in[12];
    const float* w_node_W  = (const float*)d_in[13];
    const float* w_node_b  = (const float*)d_in[14];
    const float* w_rel_W   = (const float*)d_in[15];
    const float* w_rel_b   = (const float*)d_in[16];
    const float* Wn1 = (const float*)d_in[17];
    const float* Wl1 = (const float*)d_in[18];
    const float* Wt1 = (const float*)d_in[19];
    const float* Wr1 = (const float*)d_in[20];
    const float* b1  = (const float*)d_in[21];
    const float* Wn2 = (const float*)d_in[22];
    const float* Wl2 = (const float*)d_in[23];
    const float* Wt2 = (const float*)d_in[24];
    const float* Wr2 = (const float*)d_in[25];
    const float* b2  = (const float*)d_in[26];

    float* ws = (float*)d_ws;
    size_t off = 0;
    float* rel_feat = ws + off; off += (size_t)NREL * 256;
    float* ea1      = ws + off; off += (size_t)NREL * 128;
    float* er1      = ws + off; off += (size_t)NREL * 128;
    float* er2      = ws + off; off += (size_t)NREL * 256;
    float* eb2      = ws + off; off += (size_t)NREL * 256;
    float* ent_feat = ws + off; off += (size_t)NENT * 256;
    float* ha1      = ws + off; off += (size_t)NENT * 128;
    float* hb1      = ws + off; off += (size_t)NENT * 128;
    // zeroed region (contiguous): agg1, agg2, s1, deg, gn, ge
    float* agg1 = ws + off;
    size_t zoff = off;           off += (size_t)NN * 128;
    float* agg2 = ws + off;      off += (size_t)NN * 256;
    float* s1   = ws + off;      off += (size_t)NN * 128;
    float* deg  = ws + off;      off += (size_t)NN;
    float* gn   = ws + off;      off += (size_t)GNUM * 256;
    float* ge   = ws + off;      off += (size_t)GNUM * 256;
    size_t zbytes = (off - zoff) * sizeof(float);
    hipMemsetAsync((void*)agg1, 0, zbytes, stream);

    k_rel_feat<<<NREL, 256, 0, stream>>>(rel_emb, rel_mem, w_rel_W, w_rel_b, rel_feat);
    k_rel_l1<<<NREL, 256, 0, stream>>>(rel_feat, Wn1, Wr1, ea1, er1);
    k_rel_l2<<<NREL, 256, 0, stream>>>(er1, Wr2, Wn2, er2, eb2);
    k_ent_feat<<<NENT / 16, 256, 0, stream>>>(ent_emb, ent_mem, w_node_W, w_node_b, ent_feat);
    k_ent_l1<<<NENT / 16, 256, 0, stream>>>(ent_feat, Wn1, Wl1, ha1, hb1);
    k_edge<<<NE / 16, 384, 0, stream>>>(text_emb, edge_src, edge_dst, edge_type, node_ids,
                                        Wt1, Wt2, ha1, ea1, eb2, agg1, agg2, deg);
    k_h1<<<NN * 128 / 256, 256, 0, stream>>>(agg1, deg, hb1, b1, node_ids);
    k_s1<<<NE / 2, 256, 0, stream>>>(agg1 /*=h1*/, edge_src, edge_dst, s1);
    k_h2<<<NN / 16, 256, 0, stream>>>(agg2, s1, agg1 /*=h1*/, deg, Wn2, Wl2, b2);
    k_gmax_nodes<<<dim3(GNUM, 4), 256, 0, stream>>>(agg2 /*=h2*/, node2g, gn);
    k_gmax_edges<<<dim3(GNUM, 4), 256, 0, stream>>>(er2, edge2g, edge_type, ge);
    k_out<<<(BNUM * SEQL * 512 + BNUM + 255) / 256, 256, 0, stream>>>(gn, ge, time_idx, lens,
                                                                      (float*)d_out);
}

// Round 2
// 1718.648 us; speedup vs baseline: 1.8885x; 1.8885x over previous
//
#include <hip/hip_runtime.h>

#define HD    256
#define HD2   128
#define SDIM  512
#define GNUM  64
#define NN    100000
#define NE    200000
#define NENT  20000
#define NREL  500
#define BNUM  32
#define SEQL  10

typedef __attribute__((ext_vector_type(4))) float f32x4;
typedef __attribute__((ext_vector_type(8))) short bf16x8;

__device__ __forceinline__ short to_bf(float f) {
    unsigned u = __float_as_uint(f);
    u += 0x7fff + ((u >> 16) & 1);
    return (short)(u >> 16);
}

// ---------------- small per-relation kernels ----------------

__global__ void k_rel_feat(const float* __restrict__ rel_emb, const float* __restrict__ rel_mem,
                           const float* __restrict__ W, const float* __restrict__ b,
                           float* __restrict__ rel_feat) {
    __shared__ float s[768];
    int r = blockIdx.x, j = threadIdx.x;
    for (int k = j; k < 768; k += 256)
        s[k] = (k < 512) ? rel_emb[r * 512 + k] : rel_mem[r * 256 + (k - 512)];
    __syncthreads();
    float acc = b[j];
    for (int k = 0; k < 768; ++k) acc += s[k] * W[k * 256 + j];
    rel_feat[r * 256 + j] = acc;
}

// ea1 = rel_feat @ Wn1 ; er1 = relu(rel_feat @ Wr1)
__global__ void k_rel_l1(const float* __restrict__ rel_feat, const float* __restrict__ Wn1,
                         const float* __restrict__ Wr1, float* __restrict__ ea1,
                         float* __restrict__ er1) {
    __shared__ float s[256];
    int r = blockIdx.x, j = threadIdx.x;
    s[j] = rel_feat[r * 256 + j];
    __syncthreads();
    if (j < 128) {
        float acc = 0.f;
        for (int k = 0; k < 256; ++k) acc += s[k] * Wn1[k * 128 + j];
        ea1[r * 128 + j] = acc;
    } else {
        int jj = j - 128;
        float acc = 0.f;
        for (int k = 0; k < 256; ++k) acc += s[k] * Wr1[k * 128 + jj];
        er1[r * 128 + jj] = fmaxf(acc, 0.f);
    }
}

// er2 = relu(er1 @ Wr2) ; eb2 = er1 @ Wn2
__global__ void k_rel_l2(const float* __restrict__ er1, const float* __restrict__ Wr2,
                         const float* __restrict__ Wn2, float* __restrict__ er2,
                         float* __restrict__ eb2) {
    __shared__ float s[128];
    int r = blockIdx.x, j = threadIdx.x;
    if (j < 128) s[j] = er1[r * 128 + j];
    __syncthreads();
    float a = 0.f, c = 0.f;
    for (int k = 0; k < 128; ++k) {
        float v = s[k];
        a += v * Wr2[k * 256 + j];
        c += v * Wn2[k * 256 + j];
    }
    er2[r * 256 + j] = fmaxf(a, 0.f);
    eb2[r * 256 + j] = c;
}

// ---------------- per-entity kernels (16 rows per block) ----------------

__global__ void __launch_bounds__(256) k_ent_feat(const float* __restrict__ ee,
                                                  const float* __restrict__ em,
                                                  const float* __restrict__ W,
                                                  const float* __restrict__ b,
                                                  float* __restrict__ out) {
    __shared__ float s[16 * 768];
    int r0 = blockIdx.x * 16, tid = threadIdx.x;
    for (int idx = tid; idx < 16 * 768; idx += 256) {
        int r = idx / 768, k = idx - r * 768;
        int ent = r0 + r;
        s[idx] = (k < 512) ? ee[ent * 512 + k] : em[ent * 256 + (k - 512)];
    }
    __syncthreads();
    float acc[16];
#pragma unroll
    for (int r = 0; r < 16; ++r) acc[r] = 0.f;
    int j = tid;
    for (int k = 0; k < 768; ++k) {
        float w = W[k * 256 + j];
#pragma unroll
        for (int r = 0; r < 16; ++r) acc[r] += s[r * 768 + k] * w;
    }
    float bb = b[j];
    for (int r = 0; r < 16; ++r) out[(r0 + r) * 256 + j] = acc[r] + bb;
}

// ha1 = ent_feat @ Wn1 ; hb1 = ent_feat @ Wl1
__global__ void __launch_bounds__(256) k_ent_l1(const float* __restrict__ ent_feat,
                                                const float* __restrict__ Wn1,
                                                const float* __restrict__ Wl1,
                                                float* __restrict__ ha1,
                                                float* __restrict__ hb1) {
    __shared__ float s[16 * 256];
    int r0 = blockIdx.x * 16, tid = threadIdx.x;
    for (int idx = tid; idx < 16 * 256; idx += 256) s[idx] = ent_feat[r0 * 256 + idx];
    __syncthreads();
    float acc[16];
#pragma unroll
    for (int r = 0; r < 16; ++r) acc[r] = 0.f;
    const float* Wc;
    int jj;
    if (tid < 128) { Wc = Wn1; jj = tid; } else { Wc = Wl1; jj = tid - 128; }
    for (int k = 0; k < 256; ++k) {
        float w = Wc[k * 128 + jj];
#pragma unroll
        for (int r = 0; r < 16; ++r) acc[r] += s[r * 256 + k] * w;
    }
    float* out = (tid < 128) ? ha1 : hb1;
    for (int r = 0; r < 16; ++r) out[(r0 + r) * 128 + jj] = acc[r];
}

// ---------------- weight -> bf16 fragment layout ----------------
// wbuf fragment index: ((n*16 + kk)*64 + lane), each a bf16x8.
// B-frag layout for mfma_f32_16x16x32_bf16: col = n*16 + (lane&15),
// k = kk*32 + (lane>>4)*8 + j, j=0..7.
__global__ void k_wt(const float* __restrict__ Wt1, const float* __restrict__ Wt2,
                     bf16x8* __restrict__ wbuf) {
    int n = blockIdx.x >> 4;      // 0..23 (cols 0..127 -> Wt1, 128..383 -> Wt2)
    int kk = blockIdx.x & 15;
    int lane = threadIdx.x;
    int col = (n << 4) + (lane & 15);
    int kbase = kk * 32 + (lane >> 4) * 8;
    bf16x8 v;
#pragma unroll
    for (int j = 0; j < 8; ++j) {
        int k = kbase + j;
        float w = (col < 128) ? Wt1[k * 128 + col] : Wt2[k * 256 + (col - 128)];
        v[j] = to_bf(w);
    }
    wbuf[(size_t)blockIdx.x * 64 + lane] = v;
}

// ---------------- the big fused edge kernel (MFMA) ----------------
// Per block: 64 edges. t = text[64x512] @ [Wt1|Wt2] (bf16 MFMA, f32 acc),
// then scatter msg1 = t1 + ha1[nid] - ea1[et] into agg1,
//              msg2 = t2 - eb2[et]            into agg2, deg count.
__global__ void __launch_bounds__(256, 2) k_edge(const float* __restrict__ text,
                                                 const int* __restrict__ esrc,
                                                 const int* __restrict__ edst,
                                                 const int* __restrict__ etype,
                                                 const int* __restrict__ node_ids,
                                                 const bf16x8* __restrict__ wbuf,
                                                 const float* __restrict__ ha1,
                                                 const float* __restrict__ ea1,
                                                 const float* __restrict__ eb2,
                                                 float* __restrict__ agg1,
                                                 float* __restrict__ agg2,
                                                 float* __restrict__ deg) {
    // A staged in exact fragment order: slot = kk*256 + mf*64 + g*16 + r
    // (lane = g*16+r reads slot kk*256+mf*64+lane) -> conflict-free b128 both ways.
    __shared__ bf16x8 sA[4096];   // 64 KB
    __shared__ int s_dst[64], s_et[64], s_nid[64];
    int tid = threadIdx.x;
    int e0 = blockIdx.x * 64;
    if (tid < 64) {
        int e = e0 + tid;
        s_dst[tid] = edst[e];
        s_et[tid] = etype[e];
        s_nid[tid] = node_ids[esrc[e]];
    }
    for (int it = 0; it < 16; ++it) {
        int slot = it * 256 + tid;
        int kk = slot >> 8;
        int rem = slot & 255;
        int mf = rem >> 6;
        int sub = rem & 63;
        int g = sub >> 4;
        int r = sub & 15;
        int row = mf * 16 + r;
        int k0 = kk * 32 + g * 8;
        const float4* p = reinterpret_cast<const float4*>(text + (size_t)(e0 + row) * 512 + k0);
        float4 x = p[0], y = p[1];
        bf16x8 v;
        v[0] = to_bf(x.x); v[1] = to_bf(x.y); v[2] = to_bf(x.z); v[3] = to_bf(x.w);
        v[4] = to_bf(y.x); v[5] = to_bf(y.y); v[6] = to_bf(y.z); v[7] = to_bf(y.w);
        sA[slot] = v;
    }
    __syncthreads();
    if (tid < 64) atomicAdd(&deg[s_dst[tid]], 1.0f);

    int wave = tid >> 6, lane = tid & 63;
    f32x4 acc[4][6];
#pragma unroll
    for (int mf = 0; mf < 4; ++mf)
#pragma unroll
        for (int nf = 0; nf < 6; ++nf) acc[mf][nf] = (f32x4)0.f;

    for (int kk = 0; kk < 16; ++kk) {
        bf16x8 a[4];
#pragma unroll
        for (int mf = 0; mf < 4; ++mf) a[mf] = sA[kk * 256 + mf * 64 + lane];
        bf16x8 b[6];
#pragma unroll
        for (int nf = 0; nf < 6; ++nf)
            b[nf] = wbuf[(size_t)((wave * 6 + nf) * 16 + kk) * 64 + lane];
#pragma unroll
        for (int mf = 0; mf < 4; ++mf)
#pragma unroll
            for (int nf = 0; nf < 6; ++nf)
                acc[mf][nf] = __builtin_amdgcn_mfma_f32_16x16x32_bf16(a[mf], b[nf],
                                                                      acc[mf][nf], 0, 0, 0);
    }

    // C/D layout: col = lane&15, row_in_frag = (lane>>4)*4 + q
    int gq = lane >> 4, cl = lane & 15;
#pragma unroll
    for (int mf = 0; mf < 4; ++mf) {
#pragma unroll
        for (int nf = 0; nf < 6; ++nf) {
            int c = wave * 96 + nf * 16 + cl;
            f32x4 v = acc[mf][nf];
#pragma unroll
            for (int q = 0; q < 4; ++q) {
                int row = mf * 16 + gq * 4 + q;
                int dst = s_dst[row], et = s_et[row], nid = s_nid[row];
                if (c < 128) {
                    float val = v[q] + ha1[nid * 128 + c] - ea1[et * 128 + c];
                    atomicAdd(&agg1[(size_t)dst * 128 + c], val);
                } else {
                    int c2 = c - 128;
                    float val = v[q] - eb2[et * 256 + c2];
                    atomicAdd(&agg2[(size_t)dst * 256 + c2], val);
                }
            }
        }
    }
}

// h1 = relu(agg1/deg + hb1[nid] + b1)   (in place over agg1)
__global__ void k_h1(float* __restrict__ agg1, const float* __restrict__ deg,
                     const float* __restrict__ hb1, const float* __restrict__ b1,
                     const int* __restrict__ node_ids) {
    int idx = blockIdx.x * 256 + threadIdx.x;
    int n = idx >> 7, j = idx & 127;
    float d = fmaxf(deg[n], 1.f);
    int nid = node_ids[n];
    float v = agg1[idx] / d + hb1[nid * 128 + j] + b1[j];
    agg1[idx] = fmaxf(v, 0.f);
}

// s1[dst] += h1[src]
__global__ void k_s1(const float* __restrict__ h1, const int* __restrict__ esrc,
                     const int* __restrict__ edst, float* __restrict__ s1) {
    int e = blockIdx.x * 2 + (threadIdx.x >> 7);
    int j = threadIdx.x & 127;
    int src = esrc[e], dst = edst[e];
    atomicAdd(&s1[(size_t)dst * 128 + j], h1[(size_t)src * 128 + j]);
}

// h2 = relu((agg2 + s1@Wn2)/deg + h1@Wl2 + b2)   (in place over agg2)
__global__ void __launch_bounds__(256) k_h2(float* __restrict__ agg2,
                                            const float* __restrict__ s1,
                                            const float* __restrict__ h1,
                                            const float* __restrict__ deg,
                                            const float* __restrict__ Wn2,
                                            const float* __restrict__ Wl2,
                                            const float* __restrict__ b2) {
    __shared__ float ss[16 * 128], sh[16 * 128];
    int n0 = blockIdx.x * 16, tid = threadIdx.x;
    for (int idx = tid; idx < 16 * 128; idx += 256) {
        ss[idx] = s1[(size_t)n0 * 128 + idx];
        sh[idx] = h1[(size_t)n0 * 128 + idx];
    }
    __syncthreads();
    float aa[16], ab[16];
#pragma unroll
    for (int r = 0; r < 16; ++r) { aa[r] = 0.f; ab[r] = 0.f; }
    for (int k = 0; k < 128; ++k) {
        float w1 = Wn2[k * 256 + tid];
        float w2 = Wl2[k * 256 + tid];
#pragma unroll
        for (int r = 0; r < 16; ++r) {
            aa[r] += ss[r * 128 + k] * w1;
            ab[r] += sh[r * 128 + k] * w2;
        }
    }
    float bb = b2[tid];
    for (int r = 0; r < 16; ++r) {
        int n = n0 + r;
        float d = fmaxf(deg[n], 1.f);
        float v = (agg2[(size_t)n * 256 + tid] + aa[r]) / d + ab[r] + bb;
        agg2[(size_t)n * 256 + tid] = fmaxf(v, 0.f);
    }
}

__device__ __forceinline__ int lower_bound_i(const int* __restrict__ a, int n, int v) {
    int lo = 0, hi = n;
    while (lo < hi) {
        int m = (lo + hi) >> 1;
        if (a[m] < v) lo = m + 1; else hi = m;
    }
    return lo;
}

// per-graph max over node features (h2 >= 0, so int atomicMax on float bits is valid; init 0)
__global__ void k_gmax_nodes(const float* __restrict__ h2, const int* __restrict__ n2g,
                             float* __restrict__ gn) {
    int g = blockIdx.x, q = blockIdx.y, j = threadIdx.x;
    int lo = lower_bound_i(n2g, NN, g);
    int hi = lower_bound_i(n2g, NN, g + 1);
    float mx = 0.f;
    for (int n = lo + q; n < hi; n += 16) mx = fmaxf(mx, h2[(size_t)n * 256 + j]);
    atomicMax((int*)&gn[g * 256 + j], __float_as_int(mx));
}

// per-graph max over edge features: e2[e] = er2[etype[e]]
__global__ void k_gmax_edges(const float* __restrict__ er2, const int* __restrict__ e2g,
                             const int* __restrict__ etype, float* __restrict__ ge) {
    int g = blockIdx.x, q = blockIdx.y, j = threadIdx.x;
    int lo = lower_bound_i(e2g, NE, g);
    int hi = lower_bound_i(e2g, NE, g + 1);
    float mx = 0.f;
    for (int e = lo + q; e < hi; e += 16) {
        int et = etype[e];
        mx = fmaxf(mx, er2[et * 256 + j]);
    }
    atomicMax((int*)&ge[g * 256 + j], __float_as_int(mx));
}

__global__ void k_out(const float* __restrict__ gn, const float* __restrict__ ge,
                      const int* __restrict__ time_idx, const int* __restrict__ lens,
                      float* __restrict__ out) {
    int idx = blockIdx.x * 256 + threadIdx.x;
    const int NOUT = BNUM * SEQL * 512;
    if (idx < NOUT) {
        int j = idx & 511;
        int bt = idx >> 9;
        int b = bt / SEQL, t = bt - b * SEQL;
        float v = 0.f;
        if (t < lens[b]) {
            int g = time_idx[bt];
            v = (j < 256) ? gn[g * 256 + j] : ge[g * 256 + (j - 256)];
        }
        out[idx] = v;
    } else if (idx < NOUT + BNUM) {
        int b = idx - NOUT;
        out[idx] = (float)lens[b];  // tuple output 1 read back as float32 values
    }
}

// ---------------- launch ----------------

extern "C" void kernel_launch(void* const* d_in, const int* in_sizes, int n_in,
                              void* d_out, int out_size, void* d_ws, size_t ws_size,
                              hipStream_t stream) {
    const int*   node_ids  = (const int*)d_in[0];
    const int*   edge_src  = (const int*)d_in[1];
    const int*   edge_dst  = (const int*)d_in[2];
    const int*   edge_type = (const int*)d_in[3];
    const int*   node2g    = (const int*)d_in[4];
    const int*   edge2g    = (const int*)d_in[5];
    const float* text_emb  = (const float*)d_in[6];
    const int*   time_idx  = (const int*)d_in[7];
    const int*   lens      = (const int*)d_in[8];
    const float* ent_emb   = (const float*)d_in[9];
    const float* ent_mem   = (const float*)d_in[10];
    const float* rel_emb   = (const float*)d_in[11];
    const float* rel_mem   = (const float*)d_in[12];
    const float* w_node_W  = (const float*)d_in[13];
    const float* w_node_b  = (const float*)d_in[14];
    const float* w_rel_W   = (const float*)d_in[15];
    const float* w_rel_b   = (const float*)d_in[16];
    const float* Wn1 = (const float*)d_in[17];
    const float* Wl1 = (const float*)d_in[18];
    const float* Wt1 = (const float*)d_in[19];
    const float* Wr1 = (const float*)d_in[20];
    const float* b1  = (const float*)d_in[21];
    const float* Wn2 = (const float*)d_in[22];
    const float* Wl2 = (const float*)d_in[23];
    const float* Wt2 = (const float*)d_in[24];
    const float* Wr2 = (const float*)d_in[25];
    const float* b2  = (const float*)d_in[26];

    float* ws = (float*)d_ws;
    size_t off = 0;
    float* rel_feat = ws + off; off += (size_t)NREL * 256;
    float* ea1      = ws + off; off += (size_t)NREL * 128;
    float* er1      = ws + off; off += (size_t)NREL * 128;
    float* er2      = ws + off; off += (size_t)NREL * 256;
    float* eb2      = ws + off; off += (size_t)NREL * 256;
    float* ent_feat = ws + off; off += (size_t)NENT * 256;
    float* ha1      = ws + off; off += (size_t)NENT * 128;
    float* hb1      = ws + off; off += (size_t)NENT * 128;
    bf16x8* wbuf    = (bf16x8*)(ws + off); off += (size_t)24 * 16 * 64 * 4; // 384KB as floats
    // zeroed region (contiguous): agg1, agg2, s1, deg, gn, ge
    float* agg1 = ws + off;
    size_t zoff = off;           off += (size_t)NN * 128;
    float* agg2 = ws + off;      off += (size_t)NN * 256;
    float* s1   = ws + off;      off += (size_t)NN * 128;
    float* deg  = ws + off;      off += (size_t)NN;
    float* gn   = ws + off;      off += (size_t)GNUM * 256;
    float* ge   = ws + off;      off += (size_t)GNUM * 256;
    size_t zbytes = (off - zoff) * sizeof(float);
    hipMemsetAsync((void*)agg1, 0, zbytes, stream);

    k_wt<<<384, 64, 0, stream>>>(Wt1, Wt2, wbuf);
    k_rel_feat<<<NREL, 256, 0, stream>>>(rel_emb, rel_mem, w_rel_W, w_rel_b, rel_feat);
    k_rel_l1<<<NREL, 256, 0, stream>>>(rel_feat, Wn1, Wr1, ea1, er1);
    k_rel_l2<<<NREL, 256, 0, stream>>>(er1, Wr2, Wn2, er2, eb2);
    k_ent_feat<<<NENT / 16, 256, 0, stream>>>(ent_emb, ent_mem, w_node_W, w_node_b, ent_feat);
    k_ent_l1<<<NENT / 16, 256, 0, stream>>>(ent_feat, Wn1, Wl1, ha1, hb1);
    k_edge<<<NE / 64, 256, 0, stream>>>(text_emb, edge_src, edge_dst, edge_type, node_ids,
                                        wbuf, ha1, ea1, eb2, agg1, agg2, deg);
    k_h1<<<NN * 128 / 256, 256, 0, stream>>>(agg1, deg, hb1, b1, node_ids);
    k_s1<<<NE / 2, 256, 0, stream>>>(agg1 /*=h1*/, edge_src, edge_dst, s1);
    k_h2<<<NN / 16, 256, 0, stream>>>(agg2, s1, agg1 /*=h1*/, deg, Wn2, Wl2, b2);
    k_gmax_nodes<<<dim3(GNUM, 16), 256, 0, stream>>>(agg2 /*=h2*/, node2g, gn);
    k_gmax_edges<<<dim3(GNUM, 16), 256, 0, stream>>>(er2, edge2g, edge_type, ge);
    k_out<<<(BNUM * SEQL * 512 + BNUM + 255) / 256, 256, 0, stream>>>(gn, ge, time_idx, lens,
                                                                      (float*)d_out);
}

// Round 3
// 1139.809 us; speedup vs baseline: 2.8476x; 1.5078x over previous
//
#include <hip/hip_runtime.h>

#define HD    256
#define HD2   128
#define SDIM  512
#define GNUM  64
#define NN    100000
#define NE    200000
#define NENT  20000
#define NREL  500
#define BNUM  32
#define SEQL  10

typedef __attribute__((ext_vector_type(4))) float f32x4;
typedef __attribute__((ext_vector_type(8))) short bf16x8;

__device__ __forceinline__ short to_bf(float f) {
    unsigned u = __float_as_uint(f);
    u += 0x7fff + ((u >> 16) & 1);
    return (short)(u >> 16);
}
__device__ __forceinline__ float bf_to_f(unsigned short u) {
    return __uint_as_float(((unsigned)u) << 16);
}

// ---------------- CSR build ----------------

__global__ void k_cnt(const int* __restrict__ edst, int* __restrict__ cnt) {
    int e = blockIdx.x * 256 + threadIdx.x;
    if (e < NE) atomicAdd(&cnt[edst[e]], 1);
}

__global__ void k_scan_blk(const int* __restrict__ cnt, int* __restrict__ row_off,
                           int* __restrict__ bsum) {
    __shared__ int s[256];
    int i = blockIdx.x * 256 + threadIdx.x;
    int v = cnt[i];
    s[threadIdx.x] = v;
    __syncthreads();
    for (int d = 1; d < 256; d <<= 1) {
        int t = (threadIdx.x >= d) ? s[threadIdx.x - d] : 0;
        __syncthreads();
        s[threadIdx.x] += t;
        __syncthreads();
    }
    row_off[i] = s[threadIdx.x] - v;  // exclusive
    if (threadIdx.x == 255) bsum[blockIdx.x] = s[255];
}

__global__ void k_scan_top(int* __restrict__ bsum) {  // 391 partials, 512 threads
    __shared__ int s[512];
    int v = (threadIdx.x < 391) ? bsum[threadIdx.x] : 0;
    s[threadIdx.x] = v;
    __syncthreads();
    for (int d = 1; d < 512; d <<= 1) {
        int t = (threadIdx.x >= d) ? s[threadIdx.x - d] : 0;
        __syncthreads();
        s[threadIdx.x] += t;
        __syncthreads();
    }
    if (threadIdx.x < 391) bsum[threadIdx.x] = s[threadIdx.x] - v;  // exclusive
}

__global__ void k_scan_add(int* __restrict__ row_off, const int* __restrict__ bsum,
                           int* __restrict__ cur) {
    int i = blockIdx.x * 256 + threadIdx.x;
    int v = row_off[i] + bsum[blockIdx.x];
    row_off[i] = v;
    cur[i] = v;
}

__global__ void k_fill(const int* __restrict__ edst, int* __restrict__ cur,
                       int* __restrict__ eidx) {
    int e = blockIdx.x * 256 + threadIdx.x;
    if (e < NE) {
        int pos = atomicAdd(&cur[edst[e]], 1);
        eidx[pos] = e;
    }
}

// ---------------- small per-relation kernels ----------------

__global__ void k_rel_feat(const float* __restrict__ rel_emb, const float* __restrict__ rel_mem,
                           const float* __restrict__ W, const float* __restrict__ b,
                           float* __restrict__ rel_feat) {
    __shared__ float s[768];
    int r = blockIdx.x, j = threadIdx.x;
    for (int k = j; k < 768; k += 256)
        s[k] = (k < 512) ? rel_emb[r * 512 + k] : rel_mem[r * 256 + (k - 512)];
    __syncthreads();
    float acc = b[j];
    for (int k = 0; k < 768; ++k) acc += s[k] * W[k * 256 + j];
    rel_feat[r * 256 + j] = acc;
}

__global__ void k_rel_l1(const float* __restrict__ rel_feat, const float* __restrict__ Wn1,
                         const float* __restrict__ Wr1, float* __restrict__ ea1,
                         float* __restrict__ er1) {
    __shared__ float s[256];
    int r = blockIdx.x, j = threadIdx.x;
    s[j] = rel_feat[r * 256 + j];
    __syncthreads();
    if (j < 128) {
        float acc = 0.f;
        for (int k = 0; k < 256; ++k) acc += s[k] * Wn1[k * 128 + j];
        ea1[r * 128 + j] = acc;
    } else {
        int jj = j - 128;
        float acc = 0.f;
        for (int k = 0; k < 256; ++k) acc += s[k] * Wr1[k * 128 + jj];
        er1[r * 128 + jj] = fmaxf(acc, 0.f);
    }
}

__global__ void k_rel_l2(const float* __restrict__ er1, const float* __restrict__ Wr2,
                         const float* __restrict__ Wn2, float* __restrict__ er2,
                         float* __restrict__ eb2) {
    __shared__ float s[128];
    int r = blockIdx.x, j = threadIdx.x;
    if (j < 128) s[j] = er1[r * 128 + j];
    __syncthreads();
    float a = 0.f, c = 0.f;
    for (int k = 0; k < 128; ++k) {
        float v = s[k];
        a += v * Wr2[k * 256 + j];
        c += v * Wn2[k * 256 + j];
    }
    er2[r * 256 + j] = fmaxf(a, 0.f);
    eb2[r * 256 + j] = c;
}

// ---------------- combined node weights: cw = w_node_W @ [Wn1|Wl1] ----------------

__global__ void k_cw(const float* __restrict__ wnW, const float* __restrict__ Wn1,
                     const float* __restrict__ Wl1, float* __restrict__ cw) {
    __shared__ float s[256];
    int k = blockIdx.x, j = threadIdx.x;
    s[j] = wnW[k * 256 + j];
    __syncthreads();
    float acc = 0.f;
    if (j < 128) {
        for (int m = 0; m < 256; ++m) acc += s[m] * Wn1[m * 128 + j];
    } else {
        int jj = j - 128;
        for (int m = 0; m < 256; ++m) acc += s[m] * Wl1[m * 128 + jj];
    }
    cw[k * 256 + j] = acc;
}

__global__ void k_cb(const float* __restrict__ wnb, const float* __restrict__ Wn1,
                     const float* __restrict__ Wl1, float* __restrict__ bc) {
    int j = threadIdx.x;
    float acc = 0.f;
    if (j < 128) {
        for (int m = 0; m < 256; ++m) acc += wnb[m] * Wn1[m * 128 + j];
    } else {
        int jj = j - 128;
        for (int m = 0; m < 256; ++m) acc += wnb[m] * Wl1[m * 128 + jj];
    }
    bc[j] = acc;
}

// ---------------- generic weight packer: f32 [KxN] -> bf16 B-frags ----------------
// frag id = n*KF + kk; col = n*16 + (lane&15), k = kk*32 + (lane>>4)*8 + j
__global__ void k_pack(const float* __restrict__ src, bf16x8* __restrict__ dst,
                       int K, int N) {
    int KF = K >> 5;
    int fid = blockIdx.x;
    int n = fid / KF, kk = fid - n * KF;
    int lane = threadIdx.x;
    int col = n * 16 + (lane & 15);
    int kb = kk * 32 + (lane >> 4) * 8;
    bf16x8 v;
#pragma unroll
    for (int j = 0; j < 8; ++j) v[j] = to_bf(src[(size_t)(kb + j) * N + col]);
    dst[(size_t)fid * 64 + lane] = v;
}

// ---------------- entity GEMM: [ee|em] @ cw -> ha1, hb1 ----------------

__global__ void __launch_bounds__(256) k_ent(const float* __restrict__ ee,
                                             const float* __restrict__ em,
                                             const bf16x8* __restrict__ cwf,
                                             const float* __restrict__ bc,
                                             float* __restrict__ ha1,
                                             float* __restrict__ hb1) {
    __shared__ bf16x8 sA[2048];  // 32KB: one K-chunk (256) of 64 rows
    int tid = threadIdx.x;
    int e0 = blockIdx.x * 64;
    int wave = tid >> 6, lane = tid & 63;
    f32x4 acc[4][4];
#pragma unroll
    for (int mf = 0; mf < 4; ++mf)
#pragma unroll
        for (int nf = 0; nf < 4; ++nf) acc[mf][nf] = (f32x4)0.f;

    for (int ch = 0; ch < 3; ++ch) {
        if (ch) __syncthreads();
#pragma unroll
        for (int it = 0; it < 8; ++it) {
            int row = it * 8 + (tid >> 5);
            int ent = e0 + row;
            if (ent >= NENT) ent = NENT - 1;
            int colbase = (tid & 31) * 8;
            int gc = ch * 256 + colbase;
            const float4* p = (gc < 512)
                ? (const float4*)(ee + (size_t)ent * 512 + gc)
                : (const float4*)(em + (size_t)ent * 256 + (gc - 512));
            float4 x = p[0], y = p[1];
            bf16x8 v;
            v[0] = to_bf(x.x); v[1] = to_bf(x.y); v[2] = to_bf(x.z); v[3] = to_bf(x.w);
            v[4] = to_bf(y.x); v[5] = to_bf(y.y); v[6] = to_bf(y.z); v[7] = to_bf(y.w);
            int slot = ((tid & 31) >> 2) * 256 + (row >> 4) * 64 + (tid & 3) * 16 + (row & 15);
            sA[slot] = v;
        }
        __syncthreads();
#pragma unroll
        for (int kkl = 0; kkl < 8; ++kkl) {
            bf16x8 a[4], b[4];
#pragma unroll
            for (int mf = 0; mf < 4; ++mf) a[mf] = sA[kkl * 256 + mf * 64 + lane];
#pragma unroll
            for (int nf = 0; nf < 4; ++nf)
                b[nf] = cwf[(size_t)((wave * 4 + nf) * 24 + ch * 8 + kkl) * 64 + lane];
#pragma unroll
            for (int mf = 0; mf < 4; ++mf)
#pragma unroll
                for (int nf = 0; nf < 4; ++nf)
                    acc[mf][nf] = __builtin_amdgcn_mfma_f32_16x16x32_bf16(a[mf], b[nf],
                                                                          acc[mf][nf], 0, 0, 0);
        }
    }
    int gq = lane >> 4, cl = lane & 15;
#pragma unroll
    for (int mf = 0; mf < 4; ++mf)
#pragma unroll
        for (int nf = 0; nf < 4; ++nf) {
            int c = wave * 64 + nf * 16 + cl;
            f32x4 v = acc[mf][nf];
#pragma unroll
            for (int q = 0; q < 4; ++q) {
                int m = e0 + mf * 16 + gq * 4 + q;
                if (m < NENT) {
                    float val = v[q] + bc[c];
                    if (c < 128) ha1[(size_t)m * 128 + c] = val;
                    else hb1[(size_t)m * 128 + (c - 128)] = val;
                }
            }
        }
}

// ---------------- the big edge GEMM: msg = text @ [Wt1|Wt2] + folds ----------------

__global__ void __launch_bounds__(256, 2) k_edge(const float* __restrict__ text,
                                                 const int* __restrict__ esrc,
                                                 const int* __restrict__ etype,
                                                 const int* __restrict__ node_ids,
                                                 const bf16x8* __restrict__ wtf,
                                                 const float* __restrict__ ha1,
                                                 const float* __restrict__ ea1,
                                                 const float* __restrict__ eb2,
                                                 unsigned short* __restrict__ msg) {
    __shared__ bf16x8 sA[4096];  // 64KB: 64 rows x 512 cols bf16 in frag order
    __shared__ int s_et[64], s_nid[64];
    int tid = threadIdx.x;
    int e0 = blockIdx.x * 64;
    if (tid < 64) {
        s_et[tid] = etype[e0 + tid];
        s_nid[tid] = node_ids[esrc[e0 + tid]];
    }
#pragma unroll
    for (int it = 0; it < 16; ++it) {
        int row = it * 4 + (tid >> 6);
        int lane = tid & 63;
        const float4* p = (const float4*)(text + (size_t)(e0 + row) * 512 + lane * 8);
        float4 x = p[0], y = p[1];
        bf16x8 v;
        v[0] = to_bf(x.x); v[1] = to_bf(x.y); v[2] = to_bf(x.z); v[3] = to_bf(x.w);
        v[4] = to_bf(y.x); v[5] = to_bf(y.y); v[6] = to_bf(y.z); v[7] = to_bf(y.w);
        int slot = (lane >> 2) * 256 + (row >> 4) * 64 + (lane & 3) * 16 + (row & 15);
        sA[slot] = v;
    }
    __syncthreads();

    int wave = tid >> 6, lane = tid & 63;
    f32x4 acc[4][6];
#pragma unroll
    for (int mf = 0; mf < 4; ++mf)
#pragma unroll
        for (int nf = 0; nf < 6; ++nf) acc[mf][nf] = (f32x4)0.f;

    for (int kk = 0; kk < 16; ++kk) {
        bf16x8 a[4];
#pragma unroll
        for (int mf = 0; mf < 4; ++mf) a[mf] = sA[kk * 256 + mf * 64 + lane];
        bf16x8 b[6];
#pragma unroll
        for (int nf = 0; nf < 6; ++nf)
            b[nf] = wtf[(size_t)((wave * 6 + nf) * 16 + kk) * 64 + lane];
#pragma unroll
        for (int mf = 0; mf < 4; ++mf)
#pragma unroll
            for (int nf = 0; nf < 6; ++nf)
                acc[mf][nf] = __builtin_amdgcn_mfma_f32_16x16x32_bf16(a[mf], b[nf],
                                                                      acc[mf][nf], 0, 0, 0);
    }

    int gq = lane >> 4, cl = lane & 15;
#pragma unroll
    for (int mf = 0; mf < 4; ++mf)
#pragma unroll
        for (int nf = 0; nf < 6; ++nf) {
            int c = wave * 96 + nf * 16 + cl;
            f32x4 v = acc[mf][nf];
#pragma unroll
            for (int q = 0; q < 4; ++q) {
                int row = mf * 16 + gq * 4 + q;
                int et = s_et[row], nid = s_nid[row];
                float val;
                if (c < 128) val = v[q] + ha1[(size_t)nid * 128 + c] - ea1[et * 128 + c];
                else         val = v[q] - eb2[et * 256 + (c - 128)];
                msg[(size_t)(e0 + row) * 384 + c] = (unsigned short)to_bf(val);
            }
        }
}

// ---------------- CSR gather aggregations ----------------

// h1 = relu(sum(msg[:, :128])/deg + hb1[nid] + b1) ; agg2raw = sum(msg[:, 128:384])
__global__ void __launch_bounds__(256) k_agg(const unsigned short* __restrict__ msg,
                                             const int* __restrict__ row_off,
                                             const int* __restrict__ eidx,
                                             const int* __restrict__ node_ids,
                                             const float* __restrict__ hb1,
                                             const float* __restrict__ b1,
                                             float* __restrict__ h1,
                                             float* __restrict__ agg2) {
    int n = blockIdx.x * 4 + (threadIdx.x >> 6);
    int lane = threadIdx.x & 63;
    if (n >= NN) return;
    int beg = row_off[n], end = row_off[n + 1];
    float d = fmaxf((float)(end - beg), 1.f);
    int nid = node_ids[n];
#pragma unroll
    for (int cb = 0; cb < 2; ++cb) {
        int c = cb * 64 + lane;
        float acc = 0.f;
        for (int i = beg; i < end; ++i)
            acc += bf_to_f(msg[(size_t)eidx[i] * 384 + c]);
        float v = acc / d + hb1[(size_t)nid * 128 + c] + b1[c];
        h1[(size_t)n * 128 + c] = fmaxf(v, 0.f);
    }
#pragma unroll
    for (int cb = 0; cb < 4; ++cb) {
        int c = 128 + cb * 64 + lane;
        float acc = 0.f;
        for (int i = beg; i < end; ++i)
            acc += bf_to_f(msg[(size_t)eidx[i] * 384 + c]);
        agg2[(size_t)n * 256 + (c - 128)] = acc;
    }
}

// s1[n] = sum over incoming edges of h1[src]
__global__ void __launch_bounds__(256) k_s1g(const float* __restrict__ h1,
                                             const int* __restrict__ row_off,
                                             const int* __restrict__ eidx,
                                             const int* __restrict__ esrc,
                                             float* __restrict__ s1) {
    int n = blockIdx.x * 4 + (threadIdx.x >> 6);
    int lane = threadIdx.x & 63;
    if (n >= NN) return;
    int beg = row_off[n], end = row_off[n + 1];
#pragma unroll
    for (int cb = 0; cb < 2; ++cb) {
        int c = cb * 64 + lane;
        float acc = 0.f;
        for (int i = beg; i < end; ++i)
            acc += h1[(size_t)esrc[eidx[i]] * 128 + c];
        s1[(size_t)n * 128 + c] = acc;
    }
}

// ---------------- h2 dual GEMM: relu((agg2 + s1@Wn2)/deg + h1@Wl2 + b2) ----------------

__global__ void __launch_bounds__(256) k_h2(const float* __restrict__ s1,
                                            const float* __restrict__ h1,
                                            const bf16x8* __restrict__ wn2f,
                                            const bf16x8* __restrict__ wl2f,
                                            const int* __restrict__ cnt,
                                            const float* __restrict__ b2,
                                            float* __restrict__ agg2) {
    __shared__ bf16x8 sS[1024], sH[1024];  // 16KB each
    int tid = threadIdx.x, e0 = blockIdx.x * 64;
    int wave = tid >> 6, lane = tid & 63;
#pragma unroll
    for (int it = 0; it < 4; ++it) {
        int row = it * 16 + (tid >> 4);
        int m = e0 + row;
        if (m >= NN) m = NN - 1;
        int colbase = (tid & 15) * 8;
        const float4* p1 = (const float4*)(s1 + (size_t)m * 128 + colbase);
        const float4* p2 = (const float4*)(h1 + (size_t)m * 128 + colbase);
        float4 x1 = p1[0], y1 = p1[1], x2 = p2[0], y2 = p2[1];
        bf16x8 vs, vh;
        vs[0] = to_bf(x1.x); vs[1] = to_bf(x1.y); vs[2] = to_bf(x1.z); vs[3] = to_bf(x1.w);
        vs[4] = to_bf(y1.x); vs[5] = to_bf(y1.y); vs[6] = to_bf(y1.z); vs[7] = to_bf(y1.w);
        vh[0] = to_bf(x2.x); vh[1] = to_bf(x2.y); vh[2] = to_bf(x2.z); vh[3] = to_bf(x2.w);
        vh[4] = to_bf(y2.x); vh[5] = to_bf(y2.y); vh[6] = to_bf(y2.z); vh[7] = to_bf(y2.w);
        int slot = ((tid & 15) >> 2) * 256 + (row >> 4) * 64 + (tid & 3) * 16 + (row & 15);
        sS[slot] = vs;
        sH[slot] = vh;
    }
    __syncthreads();
    f32x4 aa[4][4], ab[4][4];
#pragma unroll
    for (int mf = 0; mf < 4; ++mf)
#pragma unroll
        for (int nf = 0; nf < 4; ++nf) { aa[mf][nf] = (f32x4)0.f; ab[mf][nf] = (f32x4)0.f; }
#pragma unroll
    for (int kk = 0; kk < 4; ++kk) {
        bf16x8 a1[4], a2[4], bv1[4], bv2[4];
#pragma unroll
        for (int mf = 0; mf < 4; ++mf) {
            a1[mf] = sS[kk * 256 + mf * 64 + lane];
            a2[mf] = sH[kk * 256 + mf * 64 + lane];
        }
#pragma unroll
        for (int nf = 0; nf < 4; ++nf) {
            bv1[nf] = wn2f[(size_t)((wave * 4 + nf) * 4 + kk) * 64 + lane];
            bv2[nf] = wl2f[(size_t)((wave * 4 + nf) * 4 + kk) * 64 + lane];
        }
#pragma unroll
        for (int mf = 0; mf < 4; ++mf)
#pragma unroll
            for (int nf = 0; nf < 4; ++nf) {
                aa[mf][nf] = __builtin_amdgcn_mfma_f32_16x16x32_bf16(a1[mf], bv1[nf],
                                                                     aa[mf][nf], 0, 0, 0);
                ab[mf][nf] = __builtin_amdgcn_mfma_f32_16x16x32_bf16(a2[mf], bv2[nf],
                                                                     ab[mf][nf], 0, 0, 0);
            }
    }
    int gq = lane >> 4, cl = lane & 15;
#pragma unroll
    for (int mf = 0; mf < 4; ++mf)
#pragma unroll
        for (int nf = 0; nf < 4; ++nf) {
            int c = wave * 64 + nf * 16 + cl;
#pragma unroll
            for (int q = 0; q < 4; ++q) {
                int m = e0 + mf * 16 + gq * 4 + q;
                if (m < NN) {
                    float d = fmaxf((float)cnt[m], 1.f);
                    float v = (agg2[(size_t)m * 256 + c] + aa[mf][nf][q]) / d
                              + ab[mf][nf][q] + b2[c];
                    agg2[(size_t)m * 256 + c] = fmaxf(v, 0.f);
                }
            }
        }
}

// ---------------- per-graph max + output ----------------

__device__ __forceinline__ int lower_bound_i(const int* __restrict__ a, int n, int v) {
    int lo = 0, hi = n;
    while (lo < hi) {
        int m = (lo + hi) >> 1;
        if (a[m] < v) lo = m + 1; else hi = m;
    }
    return lo;
}

__global__ void k_gmax_nodes(const float* __restrict__ h2, const int* __restrict__ n2g,
                             float* __restrict__ gn) {
    int g = blockIdx.x, q = blockIdx.y, j = threadIdx.x;
    int lo = lower_bound_i(n2g, NN, g);
    int hi = lower_bound_i(n2g, NN, g + 1);
    float mx = 0.f;
    for (int n = lo + q; n < hi; n += 16) mx = fmaxf(mx, h2[(size_t)n * 256 + j]);
    atomicMax((int*)&gn[g * 256 + j], __float_as_int(mx));
}

__global__ void k_gmax_edges(const float* __restrict__ er2, const int* __restrict__ e2g,
                             const int* __restrict__ etype, float* __restrict__ ge) {
    int g = blockIdx.x, q = blockIdx.y, j = threadIdx.x;
    int lo = lower_bound_i(e2g, NE, g);
    int hi = lower_bound_i(e2g, NE, g + 1);
    float mx = 0.f;
    for (int e = lo + q; e < hi; e += 16) mx = fmaxf(mx, er2[etype[e] * 256 + j]);
    atomicMax((int*)&ge[g * 256 + j], __float_as_int(mx));
}

__global__ void k_out(const float* __restrict__ gn, const float* __restrict__ ge,
                      const int* __restrict__ time_idx, const int* __restrict__ lens,
                      float* __restrict__ out) {
    int idx = blockIdx.x * 256 + threadIdx.x;
    const int NOUT = BNUM * SEQL * 512;
    if (idx < NOUT) {
        int j = idx & 511;
        int bt = idx >> 9;
        int b = bt / SEQL, t = bt - b * SEQL;
        float v = 0.f;
        if (t < lens[b]) {
            int g = time_idx[bt];
            v = (j < 256) ? gn[g * 256 + j] : ge[g * 256 + (j - 256)];
        }
        out[idx] = v;
    } else if (idx < NOUT + BNUM) {
        int b = idx - NOUT;
        out[idx] = (float)lens[b];
    }
}

// ---------------- launch ----------------

extern "C" void kernel_launch(void* const* d_in, const int* in_sizes, int n_in,
                              void* d_out, int out_size, void* d_ws, size_t ws_size,
                              hipStream_t stream) {
    const int*   node_ids  = (const int*)d_in[0];
    const int*   edge_src  = (const int*)d_in[1];
    const int*   edge_dst  = (const int*)d_in[2];
    const int*   edge_type = (const int*)d_in[3];
    const int*   node2g    = (const int*)d_in[4];
    const int*   edge2g    = (const int*)d_in[5];
    const float* text_emb  = (const float*)d_in[6];
    const int*   time_idx  = (const int*)d_in[7];
    const int*   lens      = (const int*)d_in[8];
    const float* ent_emb   = (const float*)d_in[9];
    const float* ent_mem   = (const float*)d_in[10];
    const float* rel_emb   = (const float*)d_in[11];
    const float* rel_mem   = (const float*)d_in[12];
    const float* w_node_W  = (const float*)d_in[13];
    const float* w_node_b  = (const float*)d_in[14];
    const float* w_rel_W   = (const float*)d_in[15];
    const float* w_rel_b   = (const float*)d_in[16];
    const float* Wn1 = (const float*)d_in[17];
    const float* Wl1 = (const float*)d_in[18];
    const float* Wt1 = (const float*)d_in[19];
    const float* Wr1 = (const float*)d_in[20];
    const float* b1  = (const float*)d_in[21];
    const float* Wn2 = (const float*)d_in[22];
    const float* Wl2 = (const float*)d_in[23];
    const float* Wt2 = (const float*)d_in[24];
    const float* Wr2 = (const float*)d_in[25];
    const float* b2  = (const float*)d_in[26];

    float* ws = (float*)d_ws;
    size_t off = 0;
    float* rel_feat = ws + off; off += (size_t)NREL * 256;
    float* ea1      = ws + off; off += (size_t)NREL * 128;
    float* er1      = ws + off; off += (size_t)NREL * 128;
    float* er2      = ws + off; off += (size_t)NREL * 256;
    float* eb2      = ws + off; off += (size_t)NREL * 256;
    float* ha1      = ws + off; off += (size_t)NENT * 128;
    float* hb1      = ws + off; off += (size_t)NENT * 128;
    float* cw       = ws + off; off += (size_t)768 * 256;
    float* bc       = ws + off; off += 256;
    bf16x8* wtf  = (bf16x8*)(ws + off); off += (size_t)24 * 16 * 64 * 4;  // 384KB
    bf16x8* cwf  = (bf16x8*)(ws + off); off += (size_t)16 * 24 * 64 * 4;  // 384KB
    bf16x8* wn2f = (bf16x8*)(ws + off); off += (size_t)16 * 4 * 64 * 4;   // 64KB
    bf16x8* wl2f = (bf16x8*)(ws + off); off += (size_t)16 * 4 * 64 * 4;   // 64KB
    // ---- zero region: cnt | gn | ge ----
    int*   cnt = (int*)(ws + off);
    size_t zoff = off;          off += 100096;
    float* gn  = ws + off;      off += (size_t)GNUM * 256;
    float* ge  = ws + off;      off += (size_t)GNUM * 256;
    size_t zbytes = (off - zoff) * sizeof(float);
    // ---- CSR arrays ----
    int* row_off = (int*)(ws + off); off += 100352;
    int* cur     = (int*)(ws + off); off += 100096;
    int* bsum    = (int*)(ws + off); off += 512;
    int* eidx    = (int*)(ws + off); off += (size_t)NE;
    // ---- big buffers ----
    unsigned short* msg = (unsigned short*)(ws + off);
    float* s1 = ws + off;                      // s1 aliases msg (msg dead before s1 written)
    off += (size_t)NE * 384 / 2;               // 38.4M floats worth of ushorts
    float* h1   = ws + off; off += (size_t)NN * 128;
    float* agg2 = ws + off; off += (size_t)NN * 256;

    hipMemsetAsync((void*)cnt, 0, zbytes, stream);

    // CSR
    k_cnt<<<(NE + 255) / 256, 256, 0, stream>>>(edge_dst, cnt);
    k_scan_blk<<<391, 256, 0, stream>>>(cnt, row_off, bsum);
    k_scan_top<<<1, 512, 0, stream>>>(bsum);
    k_scan_add<<<391, 256, 0, stream>>>(row_off, bsum, cur);
    k_fill<<<(NE + 255) / 256, 256, 0, stream>>>(edge_dst, cur, eidx);

    // relation-side (tiny)
    k_rel_feat<<<NREL, 256, 0, stream>>>(rel_emb, rel_mem, w_rel_W, w_rel_b, rel_feat);
    k_rel_l1<<<NREL, 256, 0, stream>>>(rel_feat, Wn1, Wr1, ea1, er1);
    k_rel_l2<<<NREL, 256, 0, stream>>>(er1, Wr2, Wn2, er2, eb2);

    // combined node weights + packing
    k_cw<<<768, 256, 0, stream>>>(w_node_W, Wn1, Wl1, cw);
    k_cb<<<1, 256, 0, stream>>>(w_node_b, Wn1, Wl1, bc);
    k_pack<<<8 * 16, 64, 0, stream>>>(Wt1, wtf, 512, 128);
    k_pack<<<16 * 16, 64, 0, stream>>>(Wt2, wtf + (size_t)8 * 16 * 64, 512, 256);
    k_pack<<<16 * 24, 64, 0, stream>>>(cw, cwf, 768, 256);
    k_pack<<<16 * 4, 64, 0, stream>>>(Wn2, wn2f, 128, 256);
    k_pack<<<16 * 4, 64, 0, stream>>>(Wl2, wl2f, 128, 256);

    // entity GEMM -> ha1, hb1
    k_ent<<<(NENT + 63) / 64, 256, 0, stream>>>(ent_emb, ent_mem, cwf, bc, ha1, hb1);

    // edge GEMM -> msg (dense bf16)
    k_edge<<<NE / 64, 256, 0, stream>>>(text_emb, edge_src, edge_type, node_ids,
                                        wtf, ha1, ea1, eb2, msg);

    // CSR gather: h1 + agg2raw
    k_agg<<<NN / 4, 256, 0, stream>>>(msg, row_off, eidx, node_ids, hb1, b1, h1, agg2);
    // s1 (aliases msg region — msg no longer needed)
    k_s1g<<<NN / 4, 256, 0, stream>>>(h1, row_off, eidx, edge_src, s1);
    // h2 dual GEMM (in place over agg2)
    k_h2<<<(NN + 63) / 64, 256, 0, stream>>>(s1, h1, wn2f, wl2f, cnt, b2, agg2);

    k_gmax_nodes<<<dim3(GNUM, 16), 256, 0, stream>>>(agg2, node2g, gn);
    k_gmax_edges<<<dim3(GNUM, 16), 256, 0, stream>>>(er2, edge2g, edge_type, ge);
    k_out<<<(BNUM * SEQL * 512 + BNUM + 255) / 256, 256, 0, stream>>>(gn, ge, time_idx, lens,
                                                                      (float*)d_out);
}